// Round 4
// baseline (133.292 us; speedup 1.0000x reference)
//
#include <hip/hip_runtime.h>

typedef unsigned int uint_t;

constexpr int B = 8;
constexpr int N = 1024;
constexpr int NBLOCKS = 256;
constexpr int NTHREADS = 512;
constexpr int NWAVES = NTHREADS / 64;      // 8
constexpr int BPB = NBLOCKS / B;           // 32 blocks per batch
constexpr int SEG = N / BPB;               // 32 rows per block
constexpr int RPW = SEG / NWAVES;          // 4 rows per wave
constexpr int KPL = N / 64;                // 16 columns per lane
constexpr int MAX_ITER = 100;
constexpr float THRESH = 0.1f;
constexpr float K2 = 14.42695040888963f;         // log2(e)/EPS
constexpr float A2K = 2.0f * K2;
constexpr float NEPSLN2 = -0.06931471805599453f; // -EPS*ln2
constexpr float EPSLOGMU = -0.693146156565634f;  // EPS*log(1/N+1e-8)
constexpr uint_t MAGIC = 0xC0FFEE01u;

// ws word offsets
constexpr int OFF_U      = 0;                    // [B][N]
constexpr int OFF_V      = OFF_U + B * N;        // [B][N]
constexpr int OFF_ERRBLK = OFF_V + B * N;        // [B][32]   written-before-read
constexpr int OFF_ERRBAT = OFF_ERRBLK + 256;     // [100][8]  written-before-read
constexpr int OFF_EMDBLK = OFF_ERRBAT + 800;     // [B][32]   written-before-read
constexpr int OFF_EMDBAT = OFF_EMDBLK + 256;     // [8]       written-before-read
constexpr int OFF_ZERO   = OFF_EMDBAT + 8;       // ---- zeroed region ----
constexpr int OFF_BARFLG = OFF_ZERO;             // [8][32] uint epoch flags
constexpr int OFF_ERRFLG = OFF_BARFLG + 256;     // [8] uint (= last published it+1)
constexpr int OFF_EMDFLG = OFF_ERRFLG + 8;       // [8] uint
constexpr int OFF_ZEROEND= OFF_EMDFLG + 8;
constexpr int OFF_INIT   = OFF_ZEROEND;          // [1] uint (MAGIC; poison != MAGIC)

// ---- coherent access helpers: bypass non-coherent L1/L2, no cache-maint ops ----
__device__ __forceinline__ float gload(const float* p) {
  return __hip_atomic_load(p, __ATOMIC_RELAXED, __HIP_MEMORY_SCOPE_AGENT);
}
__device__ __forceinline__ void gstore(float* p, float v) {
  __hip_atomic_store(p, v, __ATOMIC_RELAXED, __HIP_MEMORY_SCOPE_AGENT);
}
__device__ __forceinline__ uint_t lflag(const uint_t* p) {
  return __hip_atomic_load(p, __ATOMIC_RELAXED, __HIP_MEMORY_SCOPE_AGENT);
}
__device__ __forceinline__ void sflag_rel(uint_t* p, uint_t v) {
  __hip_atomic_store(p, v, __ATOMIC_RELEASE, __HIP_MEMORY_SCOPE_AGENT);
}

__device__ __forceinline__ float wsum(float v) {
#pragma unroll
  for (int o = 32; o; o >>= 1) v += __shfl_xor(v, o);
  return v;
}
__device__ __forceinline__ float wmax(float v) {
#pragma unroll
  for (int o = 32; o; o >>= 1) v = fmaxf(v, __shfl_xor(v, o));
  return v;
}

// Deterministic block-wide sum; every thread returns the same value.
__device__ __forceinline__ float block_sum(float v, float* sh) {
  v = wsum(v);
  const int wave = threadIdx.x >> 6;
  const int lane = threadIdx.x & 63;
  if (lane == 0) sh[wave] = v;
  __syncthreads();
  float tot = 0.f;
#pragma unroll
  for (int w = 0; w < NWAVES; ++w) tot += sh[w];
  __syncthreads();
  return tot;
}

// Per-batch barrier: epoch-flag based. Arrival = one RELEASE store to a
// block-private word (no RMW serialization — R3's cost). Departure = wave 0
// polls all 32 flags with ONE vector load (lanes 0..31, RELAXED: coherent
// read, no invalidate side effects).
__device__ __forceinline__ void batch_barrier(uint_t* flg, int seg, uint_t epoch,
                                              int lane) {
  __syncthreads();
  if (threadIdx.x == 0) sflag_rel(&flg[seg], epoch);
  if (threadIdx.x < 64) {
    for (;;) {
      uint_t f = (lane < BPB) ? lflag(&flg[lane]) : epoch;
      if (__all(f >= epoch)) break;
      __builtin_amdgcn_s_sleep(1);
    }
  }
  __syncthreads();
}

// One Sinkhorn half-update in base-2 scale (K2 = log2(e)/EPS folded in).
// Column points live in REGISTERS (c[16] per lane covers all 1024 cols per
// wave) — zero LDS traffic in the inner loop. Rows are wave-uniform LDS
// broadcasts (4 per call).
template <bool TRACK>
__device__ __forceinline__ float half_update(
    const float4 (&c)[KPL], const float4* __restrict__ s_row,
    const float* __restrict__ pin, float* __restrict__ pout,
    int seg, int wave, int lane, bool pin_zero, bool first_out) {
  float p2[KPL];
#pragma unroll
  for (int k = 0; k < KPL; ++k)
    p2[k] = pin_zero ? 0.f : gload(&pin[lane + (k << 6)]) * K2;

  float err = 0.f;
#pragma unroll
  for (int rr = 0; rr < RPW; ++rr) {
    const int i = seg * SEG + wave * RPW + rr;
    float4 r4 = s_row[i];                       // wave-uniform: broadcast
    float a0 = A2K * r4.x, a1 = A2K * r4.y, a2 = A2K * r4.z;
    float X = -r4.w;                            // = K2*|row|^2
    float vals[KPL];
    float m = -3.4e38f;
#pragma unroll
    for (int k = 0; k < KPL; ++k) {
      float t = fmaf(a0, c[k].x, fmaf(a1, c[k].y, fmaf(a2, c[k].z, c[k].w)));
      float val = fminf(t - X, 0.f) + p2[k];    // = p2 - K2*C
      vals[k] = val;
      m = fmaxf(m, val);
    }
    m = wmax(m);
    float s = 0.f;
#pragma unroll
    for (int k = 0; k < KPL; ++k)
      s += __builtin_amdgcn_exp2f(vals[k] - m);
    s = wsum(s);
    float pnew = fmaf(NEPSLN2, m + __builtin_amdgcn_logf(s), EPSLOGMU);
    if (lane == 0) {
      if (TRACK) err += fabsf(pnew - (first_out ? 0.f : gload(&pout[i])));
      gstore(&pout[i], pnew);
    }
  }
  return err;
}

__global__ void __launch_bounds__(NTHREADS, 2) sinkhorn_kernel(
    const float* __restrict__ xg, const float* __restrict__ yg,
    float* __restrict__ out, float* __restrict__ ws) {
  __shared__ float4 s_x4[N];   // (x0,x1,x2, -K2*|x|^2)
  __shared__ float4 s_y4[N];
  __shared__ float sh_red[NWAVES];

  const int bid = blockIdx.x;
  const int tid = threadIdx.x;
  const int b = bid & 7;
  const int seg = bid >> 3;
  const int wave = tid >> 6;
  const int lane = tid & 63;

  float* u = ws + OFF_U + b * N;
  float* v = ws + OFF_V + b * N;
  float* err_blk = ws + OFF_ERRBLK + b * 32;
  float* err_bat = ws + OFF_ERRBAT;
  float* emd_blk = ws + OFF_EMDBLK + b * 32;
  float* emd_bat = ws + OFF_EMDBAT;
  uint_t* bar_flg = (uint_t*)(ws + OFF_BARFLG) + b * 32;
  uint_t* err_flg = (uint_t*)(ws + OFF_ERRFLG);
  uint_t* emd_flg = (uint_t*)(ws + OFF_EMDFLG);
  uint_t* init_flag = (uint_t*)(ws + OFF_INIT);

  // Stage points into LDS.
  for (int p = tid; p < N; p += NTHREADS) {
    const float* xp = xg + (size_t)(b * N + p) * 3;
    float x0 = xp[0], x1 = xp[1], x2 = xp[2];
    s_x4[p] = make_float4(x0, x1, x2, -K2 * (x0 * x0 + x1 * x1 + x2 * x2));
    const float* yp = yg + (size_t)(b * N + p) * 3;
    float y0 = yp[0], y1 = yp[1], y2 = yp[2];
    s_y4[p] = make_float4(y0, y1, y2, -K2 * (y0 * y0 + y1 * y1 + y2 * y2));
  }
  __syncthreads();

  // Column fragments into registers: per wave, lanes×KPL covers all 1024 cols.
  float4 cY[KPL], cX[KPL];
#pragma unroll
  for (int k = 0; k < KPL; ++k) {
    cY[k] = s_y4[lane + (k << 6)];   // u-update cols (y)
    cX[k] = s_x4[lane + (k << 6)];   // v-update cols (x)
  }

  // Init handshake: block 0 zeroes flag region (ws poisoned 0xAA), broadcasts
  // MAGIC. u/v need no init: iter 0 uses pin_zero/first_out (u=v=0).
  if (bid == 0) {
    uint_t* zb = (uint_t*)(ws + OFF_ZERO);
    for (int i = tid; i < OFF_ZEROEND - OFF_ZERO; i += NTHREADS)
      __hip_atomic_store(&zb[i], 0u, __ATOMIC_RELAXED, __HIP_MEMORY_SCOPE_AGENT);
    __syncthreads();
    if (tid == 0) sflag_rel(init_flag, MAGIC);
  } else if (tid == 0) {
    while (lflag(init_flag) != MAGIC) __builtin_amdgcn_s_sleep(2);
  }
  __syncthreads();

  uint_t epoch = 0;
  for (int it = 0; it < MAX_ITER; ++it) {
    // ---- u-update (+ err tracking on own rows) ----
    float my_err = half_update<true>(cY, s_x4, v, u, seg, wave, lane,
                                     /*pin_zero=*/it == 0, /*first_out=*/it == 0);
    float blk_err = block_sum(my_err, sh_red);
    if (tid == 0) gstore(&err_blk[seg], blk_err);
    ++epoch;
    batch_barrier(bar_flg, seg, epoch, lane);   // u + err_blk visible in batch

    // Publish this batch's err: propagation overlaps v-update compute.
    if (seg == 0 && tid == 0) {
      float s = 0.f;
      for (int q = 0; q < BPB; ++q) s += gload(&err_blk[q]);
      gstore(&err_bat[it * B + b], s);
      sflag_rel(&err_flg[b], (uint_t)(it + 1));
    }

    // ---- v-update (uses new u) ----
    half_update<false>(cX, s_y4, u, v, seg, wave, lane, false, false);
    ++epoch;
    batch_barrier(bar_flg, seg, epoch, lane);   // v visible in batch

    // ---- global convergence decision (uniform across all blocks) ----
    if (tid < 64) {
      const uint_t want = (uint_t)(it + 1);
      for (;;) {
        uint_t f = (lane < B) ? lflag(&err_flg[lane]) : want;
        if (__all(f >= want)) break;
        __builtin_amdgcn_s_sleep(1);
      }
      float e = (lane < B) ? gload(&err_bat[it * B + lane]) : 0.f;
      e = wsum(e);
      if (lane == 0) sh_red[0] = e;
    }
    __syncthreads();
    float tot = sh_red[0];
    __syncthreads();
    if (tot * (1.f / (B * N)) < THRESH) break;
  }

  // ---- epilogue: emd_b = sum_ij exp((u_i+v_j-C)/EPS)*C  (in K2 scale) ----
  float p2[KPL];
#pragma unroll
  for (int k = 0; k < KPL; ++k) p2[k] = gload(&v[lane + (k << 6)]) * K2;
  float acc = 0.f;
#pragma unroll
  for (int rr = 0; rr < RPW; ++rr) {
    const int i = seg * SEG + wave * RPW + rr;
    float4 r4 = s_x4[i];
    float a0 = A2K * r4.x, a1 = A2K * r4.y, a2 = A2K * r4.z;
    float X = -r4.w;
    float u2 = gload(&u[i]) * K2;
#pragma unroll
    for (int k = 0; k < KPL; ++k) {
      float t = fmaf(a0, cY[k].x, fmaf(a1, cY[k].y, fmaf(a2, cY[k].z, cY[k].w)));
      float kc = fmaxf(X - t, 0.f);   // K2*C
      acc = fmaf(__builtin_amdgcn_exp2f(u2 + p2[k] - kc), kc, acc);
    }
  }
  float blk = block_sum(acc, sh_red);
  if (tid == 0) gstore(&emd_blk[seg], blk);
  ++epoch;
  batch_barrier(bar_flg, seg, epoch, lane);
  if (seg == 0 && tid == 0) {
    float s = 0.f;
    for (int q = 0; q < BPB; ++q) s += gload(&emd_blk[q]);
    gstore(&emd_bat[b], s);
    sflag_rel(&emd_flg[b], 1u);
  }
  if (bid == 0 && tid < 64) {
    for (;;) {
      uint_t f = (lane < B) ? lflag(&emd_flg[lane]) : 1u;
      if (__all(f >= 1u)) break;
      __builtin_amdgcn_s_sleep(1);
    }
    float e = (lane < B) ? gload(&emd_bat[lane]) : 0.f;
    e = wsum(e);
    if (lane == 0) out[0] = e * (1.f / (B * K2));
  }
}

extern "C" void kernel_launch(void* const* d_in, const int* in_sizes, int n_in,
                              void* d_out, int out_size, void* d_ws, size_t ws_size,
                              hipStream_t stream) {
  const float* x = (const float*)d_in[0];
  const float* y = (const float*)d_in[1];
  float* out = (float*)d_out;
  float* ws = (float*)d_ws;
  void* args[] = { (void*)&x, (void*)&y, (void*)&out, (void*)&ws };
  // Cooperative launch only for the co-residency guarantee (no cg::grid.sync;
  // all sync is per-batch epoch flags + publish/poll over coherent atomics).
  hipLaunchCooperativeKernel((const void*)sinkhorn_kernel,
                             dim3(NBLOCKS), dim3(NTHREADS), args, 0, stream);
}